// Round 1
// baseline (484.274 us; speedup 1.0000x reference)
//
#include <hip/hip_runtime.h>
#include <hip/hip_bf16.h>

#define NB   8
#define NTOK 1024
#define DDIM 1024
#define NEXP 16
#define HDIM 4096
#define CAP  80
#define BK   64
#define LDA  (BK + 8)   // 72 bf16 = 144 B row stride: 16B-aligned rows, proven read pattern

using bf16x8 = __attribute__((ext_vector_type(8))) __bf16;
using bf16x4 = __attribute__((ext_vector_type(4))) __bf16;
using f32x4  = __attribute__((ext_vector_type(4))) float;

// ---------------- GEMM1 + exact GELU ----------------
// Hid[b][m][h] = gelu(sum_k X[b][m][k] * W1[e][k][h]),  m<80, bf16 out.
// 256 thr = 4 waves, BN=64 (1 n-tile of 16 per wave), all M=80 (5 m-tiles).
// Both operands LDS-staged bf16, double-buffered, 1 barrier/iter, reg prefetch.
// W is transpose-staged: 4x float4 coalesced loads -> bf16 -> Bt[h][k].
__global__ __launch_bounds__(256) void moe_g1(
    const float* __restrict__ X, const int* __restrict__ Y,
    const float* __restrict__ W1, __bf16* __restrict__ Hid)
{
    const int b     = blockIdx.y;
    const int e     = Y[b] & (NEXP - 1);
    const int nbase = blockIdx.x * 64;
    const int tid   = threadIdx.x;
    const int w     = tid >> 6;       // wave 0..3
    const int l     = tid & 63;
    const int q     = l >> 4;         // quad 0..3
    const int r     = l & 15;
    const int n     = nbase + w * 16 + r;
    const int kb    = tid & 15;       // B-stage: k-block of 4 rows   (write banks 2-way)
    const int hb    = tid >> 4;       // B-stage: h-block of 4 cols   (loads: 64B segments)
    const int arow  = tid >> 4;       // A-stage base row
    const int akg   = tid & 15;       // A-stage k-group

    __shared__ __bf16 As[2][CAP][LDA];   // 23.0 KB
    __shared__ __bf16 Bt[2][64][LDA];    // 18.4 KB  (transposed W tile: [h][k])

    const float* Xb  = X  + (size_t)b * NTOK * DDIM;
    const float* W1e = W1 + (size_t)e * DDIM * HDIM;

    f32x4 acc[5];
    #pragma unroll
    for (int i = 0; i < 5; ++i) acc[i] = f32x4{0.f, 0.f, 0.f, 0.f};

    float4 a_reg[5];
    float4 b_reg[4];

    // ---- prologue: load tile 0 into registers
    #pragma unroll
    for (int it = 0; it < 5; ++it)
        a_reg[it] = *(const float4*)&Xb[(size_t)(arow + 16 * it) * DDIM + akg * 4];
    #pragma unroll
    for (int kk = 0; kk < 4; ++kk)
        b_reg[kk] = *(const float4*)&W1e[(size_t)(kb * 4 + kk) * HDIM + nbase + hb * 4];

    int cur = 0;
    for (int t = 0; t < DDIM / BK; ++t) {
        // ---- stage tile t into buf[cur] (cvt fp32->bf16 in regs)
        #pragma unroll
        for (int it = 0; it < 5; ++it) {
            float4 v = a_reg[it];
            bf16x4 p = {(__bf16)v.x, (__bf16)v.y, (__bf16)v.z, (__bf16)v.w};
            *(bf16x4*)&As[cur][arow + 16 * it][akg * 4] = p;
        }
        {   // 4x4 register transpose: Bt[h][k] columns from 4 row-loads
            bf16x4 p0 = {(__bf16)b_reg[0].x, (__bf16)b_reg[1].x, (__bf16)b_reg[2].x, (__bf16)b_reg[3].x};
            bf16x4 p1 = {(__bf16)b_reg[0].y, (__bf16)b_reg[1].y, (__bf16)b_reg[2].y, (__bf16)b_reg[3].y};
            bf16x4 p2 = {(__bf16)b_reg[0].z, (__bf16)b_reg[1].z, (__bf16)b_reg[2].z, (__bf16)b_reg[3].z};
            bf16x4 p3 = {(__bf16)b_reg[0].w, (__bf16)b_reg[1].w, (__bf16)b_reg[2].w, (__bf16)b_reg[3].w};
            *(bf16x4*)&Bt[cur][hb * 4 + 0][kb * 4] = p0;
            *(bf16x4*)&Bt[cur][hb * 4 + 1][kb * 4] = p1;
            *(bf16x4*)&Bt[cur][hb * 4 + 2][kb * 4] = p2;
            *(bf16x4*)&Bt[cur][hb * 4 + 3][kb * 4] = p3;
        }
        __syncthreads();   // single barrier per iter (dbuf makes the 2nd unnecessary)

        // ---- prefetch tile t+1 (overlaps frag reads + MFMA below)
        if (t + 1 < DDIM / BK) {
            const int k0 = (t + 1) * BK;
            #pragma unroll
            for (int it = 0; it < 5; ++it)
                a_reg[it] = *(const float4*)&Xb[(size_t)(arow + 16 * it) * DDIM + k0 + akg * 4];
            #pragma unroll
            for (int kk = 0; kk < 4; ++kk)
                b_reg[kk] = *(const float4*)&W1e[(size_t)(k0 + kb * 4 + kk) * HDIM + nbase + hb * 4];
        }

        // ---- MFMA: 2 k-steps of 32, 5 m-tiles; B frag = 1 ds_read_b128
        #pragma unroll
        for (int s = 0; s < 2; ++s) {
            bf16x8 bf = *(const bf16x8*)&Bt[cur][w * 16 + r][s * 32 + q * 8];
            #pragma unroll
            for (int mt = 0; mt < 5; ++mt) {
                bf16x8 af = *(const bf16x8*)&As[cur][mt * 16 + r][s * 32 + q * 8];
                acc[mt] = __builtin_amdgcn_mfma_f32_16x16x32_bf16(af, bf, acc[mt], 0, 0, 0);
            }
        }
        cur ^= 1;
    }

    // ---- epilogue: exact GELU, bf16 store. C/D layout: col=l&15, row=q*4+reg.
    __bf16* Hb = Hid + (size_t)b * CAP * HDIM;
    #pragma unroll
    for (int mt = 0; mt < 5; ++mt)
        #pragma unroll
        for (int v = 0; v < 4; ++v) {
            int m = mt * 16 + q * 4 + v;
            float x = acc[mt][v];
            float g = 0.5f * x * (1.0f + erff(x * 0.70710678118654752f));
            Hb[(size_t)m * HDIM + n] = (__bf16)g;
        }
}

// ---------------- GEMM2 ----------------
// Out[b][m][d] += sum_h Hid[b][m][h] * W2[e][h][d]; K=4096 split 4 (blockIdx.z),
// fp32 atomicAdd into zeroed Out. Same staging structure as g1 (A already bf16).
__global__ __launch_bounds__(256) void moe_g2(
    const __bf16* __restrict__ Hid, const int* __restrict__ Y,
    const float* __restrict__ W2, float* __restrict__ Out)
{
    const int b     = blockIdx.y;
    const int e     = Y[b] & (NEXP - 1);
    const int nbase = blockIdx.x * 64;
    const int kz    = blockIdx.z * (HDIM / 4);
    const int tid   = threadIdx.x;
    const int w     = tid >> 6;
    const int l     = tid & 63;
    const int q     = l >> 4;
    const int r     = l & 15;
    const int n     = nbase + w * 16 + r;
    const int kb    = tid & 15;
    const int hb    = tid >> 4;
    const int arow  = tid >> 4;
    const int akg   = tid & 15;

    __shared__ __bf16 As[2][CAP][LDA];
    __shared__ __bf16 Bt[2][64][LDA];

    const __bf16* Hb  = Hid + (size_t)b * CAP * HDIM;
    const float*  W2e = W2  + (size_t)e * HDIM * DDIM;

    f32x4 acc[5];
    #pragma unroll
    for (int i = 0; i < 5; ++i) acc[i] = f32x4{0.f, 0.f, 0.f, 0.f};

    uint2  a_reg[5];
    float4 b_reg[4];

    // ---- prologue: tile 0
    #pragma unroll
    for (int it = 0; it < 5; ++it)
        a_reg[it] = *(const uint2*)&Hb[(size_t)(arow + 16 * it) * HDIM + kz + akg * 4];
    #pragma unroll
    for (int kk = 0; kk < 4; ++kk)
        b_reg[kk] = *(const float4*)&W2e[(size_t)(kz + kb * 4 + kk) * DDIM + nbase + hb * 4];

    int cur = 0;
    for (int t = 0; t < (HDIM / 4) / BK; ++t) {
        #pragma unroll
        for (int it = 0; it < 5; ++it)
            *(uint2*)&As[cur][arow + 16 * it][akg * 4] = a_reg[it];   // already bf16
        {
            bf16x4 p0 = {(__bf16)b_reg[0].x, (__bf16)b_reg[1].x, (__bf16)b_reg[2].x, (__bf16)b_reg[3].x};
            bf16x4 p1 = {(__bf16)b_reg[0].y, (__bf16)b_reg[1].y, (__bf16)b_reg[2].y, (__bf16)b_reg[3].y};
            bf16x4 p2 = {(__bf16)b_reg[0].z, (__bf16)b_reg[1].z, (__bf16)b_reg[2].z, (__bf16)b_reg[3].z};
            bf16x4 p3 = {(__bf16)b_reg[0].w, (__bf16)b_reg[1].w, (__bf16)b_reg[2].w, (__bf16)b_reg[3].w};
            *(bf16x4*)&Bt[cur][hb * 4 + 0][kb * 4] = p0;
            *(bf16x4*)&Bt[cur][hb * 4 + 1][kb * 4] = p1;
            *(bf16x4*)&Bt[cur][hb * 4 + 2][kb * 4] = p2;
            *(bf16x4*)&Bt[cur][hb * 4 + 3][kb * 4] = p3;
        }
        __syncthreads();

        if (t + 1 < (HDIM / 4) / BK) {
            const int k0 = kz + (t + 1) * BK;
            #pragma unroll
            for (int it = 0; it < 5; ++it)
                a_reg[it] = *(const uint2*)&Hb[(size_t)(arow + 16 * it) * HDIM + k0 + akg * 4];
            #pragma unroll
            for (int kk = 0; kk < 4; ++kk)
                b_reg[kk] = *(const float4*)&W2e[(size_t)(k0 + kb * 4 + kk) * DDIM + nbase + hb * 4];
        }

        #pragma unroll
        for (int s = 0; s < 2; ++s) {
            bf16x8 bf = *(const bf16x8*)&Bt[cur][w * 16 + r][s * 32 + q * 8];
            #pragma unroll
            for (int mt = 0; mt < 5; ++mt) {
                bf16x8 af = *(const bf16x8*)&As[cur][mt * 16 + r][s * 32 + q * 8];
                acc[mt] = __builtin_amdgcn_mfma_f32_16x16x32_bf16(af, bf, acc[mt], 0, 0, 0);
            }
        }
        cur ^= 1;
    }

    float* Ob = Out + (size_t)b * NTOK * DDIM;
    #pragma unroll
    for (int mt = 0; mt < 5; ++mt)
        #pragma unroll
        for (int v = 0; v < 4; ++v) {
            int m = mt * 16 + q * 4 + v;
            atomicAdd(&Ob[(size_t)m * DDIM + n], acc[mt][v]);
        }
}

extern "C" void kernel_launch(void* const* d_in, const int* in_sizes, int n_in,
                              void* d_out, int out_size, void* d_ws, size_t ws_size,
                              hipStream_t stream) {
    const float* X  = (const float*)d_in[0];
    const int*   Y  = (const int*)d_in[1];
    const float* W1 = (const float*)d_in[2];
    const float* W2 = (const float*)d_in[3];
    float*  Out = (float*)d_out;
    __bf16* Hid = (__bf16*)d_ws;   // 8*80*4096*2 = 5.24 MB

    // rows n >= CAP must be exactly zero; also the atomicAdd base for split-K.
    hipMemsetAsync(d_out, 0, (size_t)out_size * sizeof(float), stream);

    moe_g1<<<dim3(HDIM / 64, NB), 256, 0, stream>>>(X, Y, W1, Hid);
    moe_g2<<<dim3(DDIM / 64, NB, 4), 256, 0, stream>>>(Hid, Y, W2, Out);
}